// Round 5
// baseline (713.660 us; speedup 1.0000x reference)
//
#include <hip/hip_runtime.h>
#include <math.h>

// ---------------------------------------------------------------------------
// MemTransformerLM (Transformer-XL layer) — round 5.
// vs r4: attn i-tile 128 (frag/staging reuse across 2 strips/wave, banded-U
// with wave-independent write column, Ps/Us overlay staging -> 40KB LDS);
// TN=64 mgemm variant for N=1024 GEMMs (2x grid); merged input casts.
// ---------------------------------------------------------------------------

#define QLEN 1024
#define BSZ  4
#define DMODEL 1024
#define NHEAD 16
#define DHEAD 64
#define DINNER 4096
#define MEMLEN 1024
#define KLEN 2048

typedef __attribute__((ext_vector_type(8))) short short8;
typedef __attribute__((ext_vector_type(4))) short short4_t;
typedef __attribute__((ext_vector_type(4))) float f32x4;

__device__ __forceinline__ unsigned short f2bf(float x) {
  union { float f; unsigned u; } cv; cv.f = x;
  const unsigned u = cv.u;
  return (unsigned short)((u + 0x7FFFu + ((u >> 16) & 1u)) >> 16);
}
__device__ __forceinline__ float bf2f(unsigned short b) {
  union { unsigned u; float f; } cv; cv.u = ((unsigned)b) << 16;
  return cv.f;
}

__device__ __forceinline__ void gload16(const void* g, void* l) {
  __builtin_amdgcn_global_load_lds(
      (const __attribute__((address_space(1))) unsigned int*)g,
      (__attribute__((address_space(3))) unsigned int*)l, 16, 0, 0);
}

__device__ __forceinline__ int chidx(int row, int kc) {
  return row * 4 + (kc ^ ((row >> 1) & 3));
}

// ---------------------------------------------------------------------------
// bf16 MFMA GEMM: C[M,N] = A[M,K] @ Bt[N,K]^T. 128xTN tile, BK=32, 4 waves.
// TN=128: waves 2x2 of 64x64. TN=64: waves 2x2 of 64x32.
// MODE 0: qkv scatter -> Cb(Qh), oK(Kh), oV(Vh row-major)   [TN=128]
// MODE 1: rproj scatter -> Cb(Rk)
// MODE 2: C fp32 = acc + res ; MODE 3: Cb = relu(acc+aux) ; MODE 4: +aux+res
// ---------------------------------------------------------------------------
template<int MODE, int TN>
__global__ __launch_bounds__(256) void mgemm(
    const unsigned short* __restrict__ A, const unsigned short* __restrict__ Bt,
    float* __restrict__ C, unsigned short* __restrict__ Cb,
    const float* __restrict__ aux, const float* __restrict__ res,
    unsigned short* __restrict__ oK, unsigned short* __restrict__ oV,
    int Kdim, int N)
{
  __shared__ __align__(16) char smem[8192 + TN * 64];   // A 8KB | B TN*64B

  const int tid = threadIdx.x;
  const int lane = tid & 63, wv = tid >> 6;
  const int m0 = (int)blockIdx.y * 128, n0 = (int)blockIdx.x * TN;

  const unsigned short *gA0, *gA1, *gB0, *gB1 = nullptr;
  {
    int c = tid, m = c >> 2, kc = (c & 3) ^ ((m >> 1) & 3);
    gA0 = A + (size_t)(m0 + m) * Kdim + kc * 8;
    c = 256 + tid; m = c >> 2; kc = (c & 3) ^ ((m >> 1) & 3);
    gA1 = A + (size_t)(m0 + m) * Kdim + kc * 8;
    c = tid; int nn = c >> 2; kc = (c & 3) ^ ((nn >> 1) & 3);
    gB0 = Bt + (size_t)(n0 + nn) * Kdim + kc * 8;
    if constexpr (TN == 128) {
      c = 256 + tid; nn = c >> 2; kc = (c & 3) ^ ((nn >> 1) & 3);
      gB1 = Bt + (size_t)(n0 + nn) * Kdim + kc * 8;
    }
  }
  char* const lds0 = smem + (tid & 192) * 16;

  const int fr = lane & 15, kq = lane >> 4;
  constexpr int NJ = TN / 32;
  int aoff[4], boff[NJ];
#pragma unroll
  for (int t = 0; t < 4; ++t) {
    const int ra = (wv & 1) * 64 + t * 16 + fr;
    aoff[t] = chidx(ra, kq) * 16;
  }
#pragma unroll
  for (int t = 0; t < NJ; ++t) {
    const int rb = (wv >> 1) * (TN / 2) + t * 16 + fr;
    boff[t] = 8192 + chidx(rb, kq) * 16;
  }

  f32x4 acc[4][NJ] = {};

  for (int k0 = 0; k0 < Kdim; k0 += 32) {
    gload16(gA0, lds0);
    gload16(gA1, lds0 + 4096);
    gload16(gB0, lds0 + 8192);
    if constexpr (TN == 128) gload16(gB1, lds0 + 12288);
    gA0 += 32; gA1 += 32; gB0 += 32;
    if constexpr (TN == 128) gB1 += 32;
    __syncthreads();

    short8 af[4], bf[NJ];
#pragma unroll
    for (int t = 0; t < 4; ++t) af[t] = *(const short8*)(smem + aoff[t]);
#pragma unroll
    for (int t = 0; t < NJ; ++t) bf[t] = *(const short8*)(smem + boff[t]);
#pragma unroll
    for (int i = 0; i < 4; ++i)
#pragma unroll
      for (int j = 0; j < NJ; ++j)
        acc[i][j] = __builtin_amdgcn_mfma_f32_16x16x32_bf16(
            af[i], bf[j], acc[i][j], 0, 0, 0);
    __syncthreads();
  }

  const int rbase = m0 + (wv & 1) * 64 + (lane >> 4) * 4;
  const int cbase = n0 + (wv >> 1) * (TN / 2) + (lane & 15);
#pragma unroll
  for (int i = 0; i < 4; ++i) {
#pragma unroll
    for (int r = 0; r < 4; ++r) {
      const int grow = rbase + i * 16 + r;
#pragma unroll
      for (int j = 0; j < NJ; ++j) {
        const int gcol = cbase + j * 16;
        const float v = acc[i][j][r];
        if constexpr (MODE == 0) {
          const int kkg = grow >> 2, b2 = grow & 3;
          const int sec = gcol >> 10, hn = (gcol >> 6) & 15, d = gcol & 63;
          const unsigned short bv = f2bf(v);
          if (sec == 0) {
            if (kkg >= MEMLEN)
              Cb[((size_t)(b2 * NHEAD + hn) * QLEN + (kkg - MEMLEN)) * DHEAD + d] = bv;
          } else if (sec == 1) {
            oK[((size_t)(b2 * NHEAD + hn) * KLEN + kkg) * DHEAD + d] = bv;
          } else {
            oV[((size_t)(b2 * NHEAD + hn) * KLEN + kkg) * DHEAD + d] = bv;
          }
        } else if constexpr (MODE == 1) {
          const int hn = gcol >> 6, d = gcol & 63;
          Cb[((size_t)hn * KLEN + grow) * DHEAD + d] = f2bf(v);
        } else if constexpr (MODE == 2) {
          C[(size_t)grow * N + gcol] = v + res[(size_t)grow * N + gcol];
        } else if constexpr (MODE == 3) {
          Cb[(size_t)grow * N + gcol] = f2bf(fmaxf(v + aux[gcol], 0.f));
        } else {
          C[(size_t)grow * N + gcol] = v + aux[gcol] + res[(size_t)grow * N + gcol];
        }
      }
    }
  }
}

// ---------------------------------------------------------------------------
// Vh [bn][j=2048][d=64] bf16 -> Vt [bn][d=64][j=2048].
// ---------------------------------------------------------------------------
__global__ __launch_bounds__(256) void transpose_v(
    const unsigned short* __restrict__ Vh, unsigned short* __restrict__ Vt)
{
  __shared__ unsigned short t[64 * 80];
  const int j0 = (int)blockIdx.x * 64;
  const int bn = (int)blockIdx.y;
  const int tid = threadIdx.x;
#pragma unroll
  for (int it = 0; it < 2; ++it) {
    const int f = it * 256 + tid;
    const int j = f >> 3, d8 = (f & 7) * 8;
    const short8 v = *(const short8*)(Vh + ((size_t)bn * KLEN + j0 + j) * DHEAD + d8);
    *(short8*)(t + j * 80 + d8) = v;
  }
  __syncthreads();
  const int d = tid >> 2, jseg = (tid & 3) * 16;
  short8 o0, o1;
#pragma unroll
  for (int e = 0; e < 8; ++e) o0[e] = (short)t[(jseg + e) * 80 + d];
#pragma unroll
  for (int e = 0; e < 8; ++e) o1[e] = (short)t[(jseg + 8 + e) * 80 + d];
  unsigned short* op = Vt + ((size_t)bn * DHEAD + d) * KLEN + j0 + jseg;
  *(short8*)op = o0;
  *(short8*)(op + 8) = o1;
}

// ---------------------------------------------------------------------------
__global__ __launch_bounds__(256) void cast_bf16(
    const float* __restrict__ in, unsigned short* __restrict__ out)
{
  const size_t i = ((size_t)blockIdx.x * 256 + threadIdx.x) * 8;
  const float4 a = *(const float4*)(in + i);
  const float4 b = *(const float4*)(in + i + 4);
  short8 v;
  v[0] = (short)f2bf(a.x); v[1] = (short)f2bf(a.y);
  v[2] = (short)f2bf(a.z); v[3] = (short)f2bf(a.w);
  v[4] = (short)f2bf(b.x); v[5] = (short)f2bf(b.y);
  v[6] = (short)f2bf(b.z); v[7] = (short)f2bf(b.w);
  *(short8*)(out + i) = v;
}

// two sources -> one contiguous dest (mems | w)
__global__ __launch_bounds__(256) void cast2_bf16(
    const float* __restrict__ a, const float* __restrict__ b,
    unsigned short* __restrict__ out)
{
  const size_t i = ((size_t)blockIdx.x * 256 + threadIdx.x) * 8;
  const float* src = (i < 4194304) ? (a + i) : (b + (i - 4194304));
  const float4 x = *(const float4*)src;
  const float4 y = *(const float4*)(src + 4);
  short8 v;
  v[0] = (short)f2bf(x.x); v[1] = (short)f2bf(x.y);
  v[2] = (short)f2bf(x.z); v[3] = (short)f2bf(x.w);
  v[4] = (short)f2bf(y.x); v[5] = (short)f2bf(y.y);
  v[6] = (short)f2bf(y.z); v[7] = (short)f2bf(y.w);
  *(short8*)(out + i) = v;
}

// ---------------------------------------------------------------------------
__global__ __launch_bounds__(256) void transpose_cast(
    const float* __restrict__ in, unsigned short* __restrict__ out,
    int R, int C)
{
  __shared__ float t[64][65];
  const int r0 = (int)blockIdx.y * 64, c0 = (int)blockIdx.x * 64;
  const int tid = threadIdx.x;
  const int rr = tid >> 4, cc = (tid & 15) * 4;
#pragma unroll
  for (int it = 0; it < 4; ++it) {
    const int r = rr + it * 16;
    const float4 v = *(const float4*)(in + (size_t)(r0 + r) * C + c0 + cc);
    t[r][cc] = v.x; t[r][cc + 1] = v.y; t[r][cc + 2] = v.z; t[r][cc + 3] = v.w;
  }
  __syncthreads();
  const int oc = tid >> 2, ob = (tid & 3) * 16;
#pragma unroll
  for (int j4 = 0; j4 < 4; ++j4) {
    short4_t o;
#pragma unroll
    for (int j = 0; j < 4; ++j) o[j] = (short)f2bf(t[ob + j4 * 4 + j][oc]);
    *(short4_t*)(out + (size_t)(c0 + oc) * R + r0 + ob + j4 * 4) = o;
  }
}

// ---------------------------------------------------------------------------
// MFMA flash relative attention, i-tile 128. Block = 4 waves; wave wv owns
// q-rows [wv*32, wv*32+32) as strips is=0,1 (16 rows each). j chunks of 64.
// LDS 40KB staged: K[0,8K) 64j x 64d | V[8K,16K) 64d x 64j | R[16K,40K) 192t' x 64d
//   R window: t' = jl - il + 127 in [0,192); global r row = (j0-i0+896) + t'.
// Post-#3 overlays: Us banded strips (16x76/wave) at 16K; Ps (4KB/wave) at
//   0 (waves 0,1) and 26112 (waves 2,3).
// Banded write column: jl = m*16 + l15 + quad*4 + r - 15  (wave-independent).
// ---------------------------------------------------------------------------
__global__ __launch_bounds__(256) void attn_mfma(
    const unsigned short* __restrict__ Qh, const unsigned short* __restrict__ Kh,
    const unsigned short* __restrict__ Vt, const unsigned short* __restrict__ Rk,
    const float* __restrict__ rwb, const float* __restrict__ rrb,
    unsigned short* __restrict__ AVb)
{
  __shared__ __align__(16) char smem[40960];

  const int tid = threadIdx.x;
  const int lane = tid & 63, wv = tid >> 6;
  const int quad = lane >> 4, l15 = lane & 15;
  const int i0 = (int)blockIdx.x * 128;
  const int bn = (int)blockIdx.y, b = bn >> 4, n = bn & 15;

  const unsigned short* __restrict__ Qb = Qh + (size_t)bn * QLEN * DHEAD;
  const unsigned short* __restrict__ Kb = Kh + (size_t)bn * KLEN * DHEAD;
  const unsigned short* __restrict__ Vb = Vt + (size_t)bn * DHEAD * KLEN;
  const unsigned short* __restrict__ Rb = Rk + (size_t)n * KLEN * DHEAD;

  unsigned short* const Us = (unsigned short*)(smem + 16384) + wv * 1216; // 16x76
  unsigned short* const Ps =
      (unsigned short*)(smem + ((wv & 2) ? (26112 + (wv & 1) * 4096)
                                         : wv * 4096));                   // 32x64

  // persistent Q fragments (biases folded), per strip
  short8 qk[2][2], qr[2][2];
#pragma unroll
  for (int is = 0; is < 2; ++is) {
    const int qrow = i0 + wv * 32 + is * 16 + l15;
    const unsigned short* qp = Qb + (size_t)qrow * DHEAD + quad * 8;
    const float* wp = rwb + n * DHEAD + quad * 8;
    const float* rp = rrb + n * DHEAD + quad * 8;
#pragma unroll
    for (int ks = 0; ks < 2; ++ks) {
      const short8 q8 = *(const short8*)(qp + ks * 32);
#pragma unroll
      for (int e = 0; e < 8; ++e) {
        const float qv = bf2f((unsigned short)q8[e]);
        qk[is][ks][e] = (short)f2bf(qv + wp[ks * 32 + e]);
        qr[is][ks][e] = (short)f2bf(qv + rp[ks * 32 + e]);
      }
    }
  }

  // staging pointers (advance per chunk)
  const unsigned short* pK[2];
  const unsigned short* pV[2];
  const unsigned short* pR[6];
#pragma unroll
  for (int it = 0; it < 2; ++it) {
    const int s = it * 256 + tid, row = s >> 3, kc = (s & 7) ^ (row & 7);
    pK[it] = Kb + ((size_t)row << 6) + kc * 8;
    pV[it] = Vb + ((size_t)row << 11) + kc * 8;      // row=d here, kc=j-chunk
  }
#pragma unroll
  for (int it = 0; it < 6; ++it) {
    const int s = it * 256 + tid, row = s >> 3, kc = (s & 7) ^ (row & 7);
    pR[it] = Rb + ((size_t)(896 - i0 + row) << 6) + kc * 8;
  }

  f32x4 O[2][4] = {};
  float rden[2][4] = {};
  char* const lds0 = smem + (tid & 192) * 16;
  const int nch = (i0 >> 6) + 18;
  const int cswz = l15 & 7;                 // frag chunk-swizzle base

  for (int ch = 0; ch < nch; ++ch) {
    const int j0 = ch * 64;

    __syncthreads();   // #1: prior chunk's LDS reads complete
#pragma unroll
    for (int it = 0; it < 2; ++it) {
      gload16(pK[it], lds0 + it * 4096);
      pK[it] += 4096;
    }
#pragma unroll
    for (int it = 0; it < 2; ++it) {
      gload16(pV[it], lds0 + 8192 + it * 4096);
      pV[it] += 64;
    }
#pragma unroll
    for (int it = 0; it < 6; ++it) {
      gload16(pR[it], lds0 + 16384 + it * 4096);
      pR[it] += 4096;
    }
    __syncthreads();   // #2: staging visible

    // ---- S_K = (q+rwb)·k : shared K frags across strips ----
    f32x4 sk[2][4] = {};
#pragma unroll
    for (int jt = 0; jt < 4; ++jt) {
#pragma unroll
      for (int ks = 0; ks < 2; ++ks) {
        const int row = jt * 16 + l15;
        const int c = (ks * 4 + quad) ^ cswz;
        const short8 kf = *(const short8*)(smem + (row * 8 + c) * 16);
        sk[0][jt] = __builtin_amdgcn_mfma_f32_16x16x32_bf16(qk[0][ks], kf, sk[0][jt], 0, 0, 0);
        sk[1][jt] = __builtin_amdgcn_mfma_f32_16x16x32_bf16(qk[1][ks], kf, sk[1][jt], 0, 0, 0);
      }
    }
    // ---- U = (q+rrb)·r, union tiles s=0..5: tile tt = 6-2wv+s ----
    // strip0 uses s in [1,5] -> upk[0][s-1]; strip1 uses s in [0,4] -> upk[1][s]
    uint2 upk[2][5];
#pragma unroll
    for (int s = 0; s < 6; ++s) {
      f32x4 a0 = {0.f, 0.f, 0.f, 0.f}, a1 = {0.f, 0.f, 0.f, 0.f};
      const int row = (6 - 2 * wv + s) * 16 + l15;
#pragma unroll
      for (int ks = 0; ks < 2; ++ks) {
        const int c = (ks * 4 + quad) ^ cswz;
        const short8 rf = *(const short8*)(smem + 16384 + (row * 8 + c) * 16);
        if (s >= 1) a0 = __builtin_amdgcn_mfma_f32_16x16x32_bf16(qr[0][ks], rf, a0, 0, 0, 0);
        if (s <= 4) a1 = __builtin_amdgcn_mfma_f32_16x16x32_bf16(qr[1][ks], rf, a1, 0, 0, 0);
      }
      if (s >= 1)
        upk[0][s - 1] = make_uint2(((unsigned)f2bf(a0[1]) << 16) | f2bf(a0[0]),
                                   ((unsigned)f2bf(a0[3]) << 16) | f2bf(a0[2]));
      if (s <= 4)
        upk[1][s] = make_uint2(((unsigned)f2bf(a1[1]) << 16) | f2bf(a1[0]),
                               ((unsigned)f2bf(a1[3]) << 16) | f2bf(a1[2]));
    }
    __syncthreads();   // #3: all waves done reading K and R frags

#pragma unroll
    for (int is = 0; is < 2; ++is) {
      // banded U write: jl = m*16 + l15 + quad*4 + r - 15 (strip-independent)
#pragma unroll
      for (int m = 0; m < 5; ++m) {
#pragma unroll
        for (int r = 0; r < 4; ++r) {
          const int jl = m * 16 + l15 + quad * 4 + r - 15;
          if (jl >= 0 && jl < 64) {
            const unsigned w32 = (r & 2) ? upk[is][m].y : upk[is][m].x;
            Us[(quad * 4 + r) * 76 + jl] =
                (unsigned short)((r & 1) ? (w32 >> 16) : (w32 & 0xFFFF));
          }
        }
      }
      // P = exp((sk+u)/8), masked; write Ps strip rows is*16+m
#pragma unroll
      for (int jt = 0; jt < 4; ++jt) {
        const int jl = jt * 16 + l15;
#pragma unroll
        for (int r = 0; r < 4; ++r) {
          const int ms = quad * 4 + r;
          const int ig = i0 + wv * 32 + is * 16 + ms;
          const int dj = (j0 + jl) - ig;
          const float uv = bf2f(Us[ms * 76 + jl]);
          const float sv = (sk[is][jt][r] + uv) * 0.125f;
          const float p = (dj <= 1024) ? __expf(sv) : 0.f;
          rden[is][r] += p;
          const int m2 = is * 16 + ms;
          Ps[(m2 * 8 + ((jl >> 3) ^ (ms & 7))) * 8 + (jl & 7)] = f2bf(p);
        }
      }
    }

    // ---- O += P @ V, V frags shared across strips ----
#pragma unroll
    for (int ks = 0; ks < 2; ++ks) {
      const int cp = (ks * 4 + quad) ^ cswz;
      const short8 pf0 = *(const short8*)((const char*)Ps + ((l15 * 8 + cp) << 4));
      const short8 pf1 = *(const short8*)((const char*)Ps + (((16 + l15) * 8 + cp) << 4));
#pragma unroll
      for (int dt = 0; dt < 4; ++dt) {
        const int vr = dt * 16 + l15;
        const short8 vf = *(const short8*)(smem + 8192 + (vr * 8 + cp) * 16);
        O[0][dt] = __builtin_amdgcn_mfma_f32_16x16x32_bf16(pf0, vf, O[0][dt], 0, 0, 0);
        O[1][dt] = __builtin_amdgcn_mfma_f32_16x16x32_bf16(pf1, vf, O[1][dt], 0, 0, 0);
      }
    }
  }

  // denominator: reduce across the 16 lanes of each quad-row
#pragma unroll
  for (int m = 1; m < 16; m <<= 1)
#pragma unroll
    for (int is = 0; is < 2; ++is)
#pragma unroll
      for (int r = 0; r < 4; ++r)
        rden[is][r] += __shfl_xor(rden[is][r], m, 64);

#pragma unroll
  for (int is = 0; is < 2; ++is)
#pragma unroll
    for (int r = 0; r < 4; ++r) {
      const float inv = 1.f / rden[is][r];
      const int ig = i0 + wv * 32 + is * 16 + quad * 4 + r;
#pragma unroll
      for (int dt = 0; dt < 4; ++dt)
        AVb[((size_t)ig * BSZ + b) * DMODEL + n * DHEAD + dt * 16 + l15] =
            f2bf(O[is][dt][r] * inv);
    }
}

// ---------------------------------------------------------------------------
__global__ __launch_bounds__(256) void ln_kernel(
    float* __restrict__ X, const float* __restrict__ gw,
    const float* __restrict__ bw, unsigned short* __restrict__ bfo)
{
  const int row = blockIdx.x, tid = threadIdx.x;
  float* rp = X + (size_t)row * DMODEL;
  const float4 x = *(const float4*)(rp + tid * 4);
  float s = x.x + x.y + x.z + x.w;
  float q = x.x * x.x + x.y * x.y + x.z * x.z + x.w * x.w;
#pragma unroll
  for (int m = 1; m < 64; m <<= 1) {
    s += __shfl_xor(s, m, 64);
    q += __shfl_xor(q, m, 64);
  }
  __shared__ float ss[4], sq[4];
  if ((tid & 63) == 0) { ss[tid >> 6] = s; sq[tid >> 6] = q; }
  __syncthreads();
  s = ss[0] + ss[1] + ss[2] + ss[3];
  q = sq[0] + sq[1] + sq[2] + sq[3];
  const float mu = s * (1.f / DMODEL);
  const float var = q * (1.f / DMODEL) - mu * mu;
  const float rstd = rsqrtf(var + 1e-5f);
  const float4 g4 = *(const float4*)(gw + tid * 4);
  const float4 b4 = *(const float4*)(bw + tid * 4);
  float4 y;
  y.x = (x.x - mu) * rstd * g4.x + b4.x;
  y.y = (x.y - mu) * rstd * g4.y + b4.y;
  y.z = (x.z - mu) * rstd * g4.z + b4.z;
  y.w = (x.w - mu) * rstd * g4.w + b4.w;
  *(float4*)(rp + tid * 4) = y;
  if (bfo) {
    short4_t o;
    o[0] = (short)f2bf(y.x); o[1] = (short)f2bf(y.y);
    o[2] = (short)f2bf(y.z); o[3] = (short)f2bf(y.w);
    *(short4_t*)(bfo + (size_t)row * DMODEL + tid * 4) = o;
  }
}

// ---------------------------------------------------------------------------
extern "C" void kernel_launch(void* const* d_in, const int* in_sizes, int n_in,
                              void* d_out, int out_size, void* d_ws,
                              size_t ws_size, hipStream_t stream)
{
  const float* w       = (const float*)d_in[0];
  const float* r       = (const float*)d_in[1];
  const float* mems    = (const float*)d_in[2];
  const float* qkv_w   = (const float*)d_in[3];
  const float* r_net_w = (const float*)d_in[4];
  const float* o_w     = (const float*)d_in[5];
  const float* r_w_bias= (const float*)d_in[6];
  const float* r_r_bias= (const float*)d_in[7];
  const float* ln1_g   = (const float*)d_in[8];
  const float* ln1_b   = (const float*)d_in[9];
  const float* ff_w1   = (const float*)d_in[10];
  const float* ff_b1   = (const float*)d_in[11];
  const float* ff_w2   = (const float*)d_in[12];
  const float* ff_b2   = (const float*)d_in[13];
  const float* ln2_g   = (const float*)d_in[14];
  const float* ln2_b   = (const float*)d_in[15];
  float* out = (float*)d_out;

  // ---- workspace carve-up ----
  float* X1 = (float*)d_ws;                               // 4,194,304 f32
  unsigned short* Qh   = (unsigned short*)(X1 + 4194304); // 4,194,304 bf16
  unsigned short* Kh   = Qh + 4194304;                    // 8,388,608
  unsigned short* Vt   = Kh + 8388608;                    // 8,388,608
  unsigned short* Rk   = Vt + 8388608;                    // 2,097,152 (+8192 pad)
  unsigned short* Xcat = Rk + 2097152 + 8192;             // 8,388,608
  unsigned short* Wqkv = Xcat + 8388608;                  // 3,145,728
  unsigned short* Wr   = Wqkv + 3145728;                  // 1,048,576
  unsigned short* Wo   = Wr + 1048576;                    // 1,048,576
  unsigned short* W1   = Wo + 1048576;                    // 4,194,304
  unsigned short* W2   = W1 + 4194304;                    // 4,194,304
  unsigned short* Vh   = (unsigned short*)X1;  // borrow X1 (dead until oproj)
  unsigned short* Rb16 = Xcat;                 // alias (Xcat dead after qkv)
  unsigned short* AVb  = Xcat + 4194304;       // alias, disjoint from Rb16
  unsigned short* X1b  = Qh;                   // alias (Qh dead after attn)
  unsigned short* H    = Kh;                   // alias (spans Kh+Vt)

  const dim3 blk(256);

  cast2_bf16<<<dim3(4096), blk, 0, stream>>>(mems, w, Xcat);
  transpose_cast<<<dim3(48, 16), blk, 0, stream>>>(qkv_w, Wqkv, 1024, 3072);
  transpose_cast<<<dim3(16, 16), blk, 0, stream>>>(r_net_w, Wr, 1024, 1024);
  transpose_cast<<<dim3(16, 16), blk, 0, stream>>>(o_w, Wo, 1024, 1024);
  transpose_cast<<<dim3(64, 16), blk, 0, stream>>>(ff_w1, W1, 1024, 4096);
  transpose_cast<<<dim3(16, 64), blk, 0, stream>>>(ff_w2, W2, 4096, 1024);

  // 1. QKV -> Qh/Kh bf16, Vh row-major
  mgemm<0, 128><<<dim3(24, 64), blk, 0, stream>>>(
      Xcat, Wqkv, nullptr, Qh, nullptr, nullptr, Kh, Vh, DMODEL, 3 * DMODEL);
  transpose_v<<<dim3(32, 64), blk, 0, stream>>>(Vh, Vt);
  // 2. R projection -> Rk bf16
  cast_bf16<<<dim3(1024), blk, 0, stream>>>(r, Rb16);
  mgemm<1, 64><<<dim3(16, 16), blk, 0, stream>>>(
      Rb16, Wr, nullptr, Rk, nullptr, nullptr, nullptr, nullptr, DMODEL, DMODEL);
  // 3. MFMA flash attention (i-tile 128) -> AVb bf16
  attn_mfma<<<dim3(8, 64), blk, 0, stream>>>(
      Qh, Kh, Vt, Rk, r_w_bias, r_r_bias, AVb);
  // 4. o-proj + residual -> X1 fp32; LN1 (+X1b bf16)
  mgemm<2, 64><<<dim3(16, 32), blk, 0, stream>>>(
      AVb, Wo, X1, nullptr, nullptr, w, nullptr, nullptr, DMODEL, DMODEL);
  ln_kernel<<<dim3(4096), blk, 0, stream>>>(X1, ln1_g, ln1_b, X1b);
  // 5. FFN up + relu -> H bf16
  mgemm<3, 128><<<dim3(32, 32), blk, 0, stream>>>(
      X1b, W1, nullptr, H, ff_b1, nullptr, nullptr, nullptr, DMODEL, DINNER);
  // 6. FFN down + bias + residual -> out fp32; LN2
  mgemm<4, 64><<<dim3(16, 32), blk, 0, stream>>>(
      H, W2, out, nullptr, ff_b2, X1, nullptr, nullptr, DINNER, DMODEL);
  ln_kernel<<<dim3(4096), blk, 0, stream>>>(out, ln2_g, ln2_b, nullptr);

  (void)in_sizes; (void)n_in; (void)out_size; (void)ws_size;
}

// Round 6
// 605.278 us; speedup vs baseline: 1.1791x; 1.1791x over previous
//
#include <hip/hip_runtime.h>
#include <math.h>

// ---------------------------------------------------------------------------
// MemTransformerLM (Transformer-XL layer) — round 6.
// attn: r4 geometry (i-tile 64) + j-split 2-way with fp32 additive partials,
// U-band via ds_bpermute (no Us LDS), R ring-buffer (phys row = grow & 127),
// wave-private Ps region -> 2 barriers/chunk, 40KB LDS, 4 blocks/CU.
// Non-attn: r5 kernels (TN templates), prep launches merged into 2.
// ---------------------------------------------------------------------------

#define QLEN 1024
#define BSZ  4
#define DMODEL 1024
#define NHEAD 16
#define DHEAD 64
#define DINNER 4096
#define MEMLEN 1024
#define KLEN 2048

typedef __attribute__((ext_vector_type(8))) short short8;
typedef __attribute__((ext_vector_type(4))) short short4_t;
typedef __attribute__((ext_vector_type(4))) float f32x4;

__device__ __forceinline__ unsigned short f2bf(float x) {
  union { float f; unsigned u; } cv; cv.f = x;
  const unsigned u = cv.u;
  return (unsigned short)((u + 0x7FFFu + ((u >> 16) & 1u)) >> 16);
}
__device__ __forceinline__ float bf2f(unsigned short b) {
  union { unsigned u; float f; } cv; cv.u = ((unsigned)b) << 16;
  return cv.f;
}

__device__ __forceinline__ void gload16(const void* g, void* l) {
  __builtin_amdgcn_global_load_lds(
      (const __attribute__((address_space(1))) unsigned int*)g,
      (__attribute__((address_space(3))) unsigned int*)l, 16, 0, 0);
}

__device__ __forceinline__ int chidx(int row, int kc) {
  return row * 4 + (kc ^ ((row >> 1) & 3));
}

// ---------------------------------------------------------------------------
// bf16 MFMA GEMM: C[M,N] = A[M,K] @ Bt[N,K]^T. 128xTN tile, BK=32, 4 waves.
// ---------------------------------------------------------------------------
template<int MODE, int TN>
__global__ __launch_bounds__(256) void mgemm(
    const unsigned short* __restrict__ A, const unsigned short* __restrict__ Bt,
    float* __restrict__ C, unsigned short* __restrict__ Cb,
    const float* __restrict__ aux, const float* __restrict__ res,
    unsigned short* __restrict__ oK, unsigned short* __restrict__ oV,
    int Kdim, int N)
{
  __shared__ __align__(16) char smem[8192 + TN * 64];

  const int tid = threadIdx.x;
  const int lane = tid & 63, wv = tid >> 6;
  const int m0 = (int)blockIdx.y * 128, n0 = (int)blockIdx.x * TN;

  const unsigned short *gA0, *gA1, *gB0, *gB1 = nullptr;
  {
    int c = tid, m = c >> 2, kc = (c & 3) ^ ((m >> 1) & 3);
    gA0 = A + (size_t)(m0 + m) * Kdim + kc * 8;
    c = 256 + tid; m = c >> 2; kc = (c & 3) ^ ((m >> 1) & 3);
    gA1 = A + (size_t)(m0 + m) * Kdim + kc * 8;
    c = tid; int nn = c >> 2; kc = (c & 3) ^ ((nn >> 1) & 3);
    gB0 = Bt + (size_t)(n0 + nn) * Kdim + kc * 8;
    if constexpr (TN == 128) {
      c = 256 + tid; nn = c >> 2; kc = (c & 3) ^ ((nn >> 1) & 3);
      gB1 = Bt + (size_t)(n0 + nn) * Kdim + kc * 8;
    }
  }
  char* const lds0 = smem + (tid & 192) * 16;

  const int fr = lane & 15, kq = lane >> 4;
  constexpr int NJ = TN / 32;
  int aoff[4], boff[NJ];
#pragma unroll
  for (int t = 0; t < 4; ++t) {
    const int ra = (wv & 1) * 64 + t * 16 + fr;
    aoff[t] = chidx(ra, kq) * 16;
  }
#pragma unroll
  for (int t = 0; t < NJ; ++t) {
    const int rb = (wv >> 1) * (TN / 2) + t * 16 + fr;
    boff[t] = 8192 + chidx(rb, kq) * 16;
  }

  f32x4 acc[4][NJ] = {};

  for (int k0 = 0; k0 < Kdim; k0 += 32) {
    gload16(gA0, lds0);
    gload16(gA1, lds0 + 4096);
    gload16(gB0, lds0 + 8192);
    if constexpr (TN == 128) gload16(gB1, lds0 + 12288);
    gA0 += 32; gA1 += 32; gB0 += 32;
    if constexpr (TN == 128) gB1 += 32;
    __syncthreads();

    short8 af[4], bf[NJ];
#pragma unroll
    for (int t = 0; t < 4; ++t) af[t] = *(const short8*)(smem + aoff[t]);
#pragma unroll
    for (int t = 0; t < NJ; ++t) bf[t] = *(const short8*)(smem + boff[t]);
#pragma unroll
    for (int i = 0; i < 4; ++i)
#pragma unroll
      for (int j = 0; j < NJ; ++j)
        acc[i][j] = __builtin_amdgcn_mfma_f32_16x16x32_bf16(
            af[i], bf[j], acc[i][j], 0, 0, 0);
    __syncthreads();
  }

  const int rbase = m0 + (wv & 1) * 64 + (lane >> 4) * 4;
  const int cbase = n0 + (wv >> 1) * (TN / 2) + (lane & 15);
#pragma unroll
  for (int i = 0; i < 4; ++i) {
#pragma unroll
    for (int r = 0; r < 4; ++r) {
      const int grow = rbase + i * 16 + r;
#pragma unroll
      for (int j = 0; j < NJ; ++j) {
        const int gcol = cbase + j * 16;
        const float v = acc[i][j][r];
        if constexpr (MODE == 0) {
          const int kkg = grow >> 2, b2 = grow & 3;
          const int sec = gcol >> 10, hn = (gcol >> 6) & 15, d = gcol & 63;
          const unsigned short bv = f2bf(v);
          if (sec == 0) {
            if (kkg >= MEMLEN)
              Cb[((size_t)(b2 * NHEAD + hn) * QLEN + (kkg - MEMLEN)) * DHEAD + d] = bv;
          } else if (sec == 1) {
            oK[((size_t)(b2 * NHEAD + hn) * KLEN + kkg) * DHEAD + d] = bv;
          } else {
            oV[((size_t)(b2 * NHEAD + hn) * KLEN + kkg) * DHEAD + d] = bv;
          }
        } else if constexpr (MODE == 1) {
          const int hn = gcol >> 6, d = gcol & 63;
          Cb[((size_t)hn * KLEN + grow) * DHEAD + d] = f2bf(v);
        } else if constexpr (MODE == 2) {
          C[(size_t)grow * N + gcol] = v + res[(size_t)grow * N + gcol];
        } else if constexpr (MODE == 3) {
          Cb[(size_t)grow * N + gcol] = f2bf(fmaxf(v + aux[gcol], 0.f));
        } else {
          C[(size_t)grow * N + gcol] = v + aux[gcol] + res[(size_t)grow * N + gcol];
        }
      }
    }
  }
}

// ---------------------------------------------------------------------------
// Vh [bn][j][d] bf16 -> Vt [bn][d][j] bf16.
// ---------------------------------------------------------------------------
__global__ __launch_bounds__(256) void transpose_v(
    const unsigned short* __restrict__ Vh, unsigned short* __restrict__ Vt)
{
  __shared__ unsigned short t[64 * 80];
  const int j0 = (int)blockIdx.x * 64;
  const int bn = (int)blockIdx.y;
  const int tid = threadIdx.x;
#pragma unroll
  for (int it = 0; it < 2; ++it) {
    const int f = it * 256 + tid;
    const int j = f >> 3, d8 = (f & 7) * 8;
    const short8 v = *(const short8*)(Vh + ((size_t)bn * KLEN + j0 + j) * DHEAD + d8);
    *(short8*)(t + j * 80 + d8) = v;
  }
  __syncthreads();
  const int d = tid >> 2, jseg = (tid & 3) * 16;
  short8 o0, o1;
#pragma unroll
  for (int e = 0; e < 8; ++e) o0[e] = (short)t[(jseg + e) * 80 + d];
#pragma unroll
  for (int e = 0; e < 8; ++e) o1[e] = (short)t[(jseg + 8 + e) * 80 + d];
  unsigned short* op = Vt + ((size_t)bn * DHEAD + d) * KLEN + j0 + jseg;
  *(short8*)op = o0;
  *(short8*)(op + 8) = o1;
}

// ---------------------------------------------------------------------------
// merged input casts: mems|w -> Xcat, r -> Rb16. grid 5120.
// ---------------------------------------------------------------------------
__global__ __launch_bounds__(256) void cast_all(
    const float* __restrict__ mems, const float* __restrict__ w,
    const float* __restrict__ r, unsigned short* __restrict__ Xcat,
    unsigned short* __restrict__ Rb16)
{
  const size_t i = ((size_t)blockIdx.x * 256 + threadIdx.x) * 8;
  const float* src;
  unsigned short* dst;
  if (i < 4194304)       { src = mems + i;          dst = Xcat + i; }
  else if (i < 8388608)  { src = w + (i - 4194304); dst = Xcat + i; }
  else                   { src = r + (i - 8388608); dst = Rb16 + (i - 8388608); }
  const float4 x = *(const float4*)src;
  const float4 y = *(const float4*)(src + 4);
  short8 v;
  v[0] = (short)f2bf(x.x); v[1] = (short)f2bf(x.y);
  v[2] = (short)f2bf(x.z); v[3] = (short)f2bf(x.w);
  v[4] = (short)f2bf(y.x); v[5] = (short)f2bf(y.y);
  v[6] = (short)f2bf(y.z); v[7] = (short)f2bf(y.w);
  *(short8*)dst = v;
}

// ---------------------------------------------------------------------------
// merged weight transposes: fp32 [R][C] -> bf16 [C][R], 5 weights. grid 3328.
// ---------------------------------------------------------------------------
__global__ __launch_bounds__(256) void transpose_all(
    const float* __restrict__ qkv_w, const float* __restrict__ r_net_w,
    const float* __restrict__ o_w, const float* __restrict__ ff_w1,
    const float* __restrict__ ff_w2,
    unsigned short* __restrict__ Wqkv, unsigned short* __restrict__ Wr,
    unsigned short* __restrict__ Wo, unsigned short* __restrict__ W1,
    unsigned short* __restrict__ W2)
{
  const int bid = (int)blockIdx.x;
  const float* in; unsigned short* out; int R, C, xt, loc;
  if (bid < 768)        { in = qkv_w;   out = Wqkv; R = 1024; C = 3072; xt = 48; loc = bid; }
  else if (bid < 1024)  { in = r_net_w; out = Wr;   R = 1024; C = 1024; xt = 16; loc = bid - 768; }
  else if (bid < 1280)  { in = o_w;     out = Wo;   R = 1024; C = 1024; xt = 16; loc = bid - 1024; }
  else if (bid < 2304)  { in = ff_w1;   out = W1;   R = 1024; C = 4096; xt = 64; loc = bid - 1280; }
  else                  { in = ff_w2;   out = W2;   R = 4096; C = 1024; xt = 16; loc = bid - 2304; }
  const int c0 = (loc % xt) * 64, r0 = (loc / xt) * 64;

  __shared__ float t[64][65];
  const int tid = threadIdx.x;
  const int rr = tid >> 4, cc = (tid & 15) * 4;
#pragma unroll
  for (int it = 0; it < 4; ++it) {
    const int rw = rr + it * 16;
    const float4 v = *(const float4*)(in + (size_t)(r0 + rw) * C + c0 + cc);
    t[rw][cc] = v.x; t[rw][cc + 1] = v.y; t[rw][cc + 2] = v.z; t[rw][cc + 3] = v.w;
  }
  __syncthreads();
  const int oc = tid >> 2, ob = (tid & 3) * 16;
#pragma unroll
  for (int j4 = 0; j4 < 4; ++j4) {
    short4_t o;
#pragma unroll
    for (int j = 0; j < 4; ++j) o[j] = (short)f2bf(t[ob + j4 * 4 + j][oc]);
    *(short4_t*)(out + (size_t)(c0 + oc) * R + r0 + ob + j4 * 4) = o;
  }
}

// ---------------------------------------------------------------------------
// MFMA flash relative attention, r6.
// Block = 4 waves; i-tile 64 (wave wv owns rows [wv*16, wv*16+16)); j-split 2.
// grid (32, 64): it = bx>>1, sp = bx&1; chunks [lo,hi) of nch = 17+it.
// LDS 40KB: K 8K @0 | V 8K @8K | R-ring 16K @16K (phys row = grow & 127) |
//           Ps 8K @32K (wave-private rows -> no barrier).
// U band: uu[5] MFMA tiles; gather via bpermute:
//   E = l15 - quad*4 - r + 15; val = uu[jt + (E>=16)][r] from lane (lane&48)|(E&15).
// Output: unnormalized fp32 Opart + row denominators (combined by attn_combine).
// ---------------------------------------------------------------------------
__global__ __launch_bounds__(256, 4) void attn_mfma(
    const unsigned short* __restrict__ Qh, const unsigned short* __restrict__ Kh,
    const unsigned short* __restrict__ Vt, const unsigned short* __restrict__ Rk,
    const float* __restrict__ rwb, const float* __restrict__ rrb,
    float* __restrict__ Opart0, float* __restrict__ Opart1,
    float* __restrict__ den0, float* __restrict__ den1)
{
  __shared__ __align__(16) char smem[40960];
  unsigned short* const Ps = (unsigned short*)(smem + 32768);

  const int tid = threadIdx.x;
  const int lane = tid & 63, wv = tid >> 6;
  const int quad = lane >> 4, l15 = lane & 15;
  const int it = (int)blockIdx.x >> 1, sp = (int)blockIdx.x & 1;
  const int i0 = it * 64;
  const int bn = (int)blockIdx.y, n = bn & 15;

  const int nch = 17 + it;
  const int h = (nch + 1) >> 1;
  const int lo = sp ? h : 0, hi = sp ? nch : h;

  const unsigned short* __restrict__ Qb = Qh + (size_t)bn * QLEN * DHEAD;
  const unsigned short* __restrict__ Kb = Kh + (size_t)bn * KLEN * DHEAD;
  const unsigned short* __restrict__ Vb = Vt + (size_t)bn * DHEAD * KLEN;
  const unsigned short* __restrict__ Rb = Rk + (size_t)n * KLEN * DHEAD;

  // persistent Q fragments with biases folded
  short8 qk[2], qr[2];
  {
    const int qrow = i0 + wv * 16 + l15;
    const unsigned short* qp = Qb + (size_t)qrow * DHEAD + quad * 8;
    const float* wp = rwb + n * DHEAD + quad * 8;
    const float* rp = rrb + n * DHEAD + quad * 8;
#pragma unroll
    for (int ks = 0; ks < 2; ++ks) {
      const short8 q8 = *(const short8*)(qp + ks * 32);
#pragma unroll
      for (int e = 0; e < 8; ++e) {
        const float qv = bf2f((unsigned short)q8[e]);
        qk[ks][e] = (short)f2bf(qv + wp[ks * 32 + e]);
        qr[ks][e] = (short)f2bf(qv + rp[ks * 32 + e]);
      }
    }
  }

  // bpermute lane maps + selectors (per register r)
  int srcl[4];
  bool condE[4];
#pragma unroll
  for (int r = 0; r < 4; ++r) {
    const int E = l15 - quad * 4 - r + 15;           // in [0,30]
    srcl[r] = (lane & 48) | (E & 15);
    condE[r] = (E >= 16);
  }

  f32x4 O[4] = {};
  float rden[4] = {0.f, 0.f, 0.f, 0.f};
  char* const lds0 = smem + (tid & 192) * 16;

  for (int ch = lo; ch < hi; ++ch) {
    const int j0 = ch * 64;
    const int gw = j0 - i0 + 960;        // R window start (global row), mult 64

    __syncthreads();   // #1: prior chunk's LDS reads complete before restage

    // ---- stage K (8KB @0), V (8KB @8K) ----
#pragma unroll
    for (int t2 = 0; t2 < 2; ++t2) {
      const int s = t2 * 256 + tid;
      const int row = s >> 3, kc = (s & 7) ^ (row & 7);
      gload16(Kb + (((size_t)(j0 + row)) << 6) + kc * 8, lds0 + t2 * 4096);
    }
#pragma unroll
    for (int t2 = 0; t2 < 2; ++t2) {
      const int s = t2 * 256 + tid;
      const int row = s >> 3, kc = (s & 7) ^ (row & 7);
      gload16(Vb + (((size_t)row) << 11) + j0 + kc * 8, lds0 + 8192 + t2 * 4096);
    }
    // ---- stage R ring: first chunk full 128 rows, else top 64 rows ----
    if (ch == lo) {
#pragma unroll
      for (int t2 = 0; t2 < 4; ++t2) {
        const int rr = t2 * 32 + (tid >> 3);
        const int gr = gw + rr;
        const int kc = (tid & 7) ^ (rr & 7);
        const int pb = ((gw + t2 * 32) & 127) * 128;
        gload16(Rb + (((size_t)gr) << 6) + kc * 8,
                smem + 16384 + pb + (tid & 192) * 16);
      }
    } else {
#pragma unroll
      for (int t2 = 0; t2 < 2; ++t2) {
        const int rr = t2 * 32 + (tid >> 3);
        const int gr = gw + 64 + rr;
        const int kc = (tid & 7) ^ (rr & 7);
        const int pb = ((gw + 64 + t2 * 32) & 127) * 128;
        gload16(Rb + (((size_t)gr) << 6) + kc * 8,
                smem + 16384 + pb + (tid & 192) * 16);
      }
    }
    __syncthreads();   // #2: staging visible

    // ---- S_K = (q+rwb)·k ----
    f32x4 sk[4];
#pragma unroll
    for (int jt = 0; jt < 4; ++jt) {
      f32x4 a = {0.f, 0.f, 0.f, 0.f};
#pragma unroll
      for (int ks = 0; ks < 2; ++ks) {
        const int frr = jt * 16 + l15;
        const int c = (ks * 4 + quad) ^ (l15 & 7);
        const short8 kf = *(const short8*)(smem + (frr * 8 + c) * 16);
        a = __builtin_amdgcn_mfma_f32_16x16x32_bf16(qk[ks], kf, a, 0, 0, 0);
      }
      sk[jt] = a;
    }
    // ---- U = (q+rrb)·r band: 5 tiles (window-relative tiles 3-wv+s) ----
    f32x4 uu[5];
#pragma unroll
    for (int s = 0; s < 5; ++s) {
      f32x4 a = {0.f, 0.f, 0.f, 0.f};
      const int frr = (gw + (3 - wv + s) * 16 + l15) & 127;   // phys ring row
#pragma unroll
      for (int ks = 0; ks < 2; ++ks) {
        const int c = (ks * 4 + quad) ^ (l15 & 7);
        const short8 rf = *(const short8*)(smem + 16384 + (frr * 8 + c) * 16);
        a = __builtin_amdgcn_mfma_f32_16x16x32_bf16(qr[ks], rf, a, 0, 0, 0);
      }
      uu[s] = a;
    }

    // ---- band rotate via bpermute: rot[s][r] = uu[s][r] from lane srcl[r] ----
    float rot[5][4];
#pragma unroll
    for (int s = 0; s < 5; ++s)
#pragma unroll
      for (int r = 0; r < 4; ++r)
        rot[s][r] = __shfl(uu[s][r], srcl[r], 64);

    // ---- P = exp((S_K + U)/8), masked; Ps wave-private (no barrier) ----
#pragma unroll
    for (int jt = 0; jt < 4; ++jt) {
      const int jl = jt * 16 + l15;
#pragma unroll
      for (int r = 0; r < 4; ++r) {
        const int il = wv * 16 + quad * 4 + r;
        const int dj = (j0 + jl) - (i0 + il);
        const float uv = condE[r] ? rot[jt + 1][r] : rot[jt][r];
        const float sv = (sk[jt][r] + uv) * 0.125f;
        const float p = (dj <= 1024) ? __expf(sv) : 0.f;
        rden[r] += p;
        Ps[(il * 8 + ((jl >> 3) ^ (il & 7))) * 8 + (jl & 7)] = f2bf(p);
      }
    }

    // ---- O += P @ V (wave-private P strip) ----
#pragma unroll
    for (int ks = 0; ks < 2; ++ks) {
      const int frp = wv * 16 + l15;
      const int cp = (ks * 4 + quad) ^ (l15 & 7);
      const short8 pf = *(const short8*)(smem + 32768 + (frp * 8 + cp) * 16);
#pragma unroll
      for (int dt = 0; dt < 4; ++dt) {
        const int vr = dt * 16 + l15;
        const short8 vf = *(const short8*)(smem + 8192 + (vr * 8 + cp) * 16);
        O[dt] = __builtin_amdgcn_mfma_f32_16x16x32_bf16(pf, vf, O[dt], 0, 0, 0);
      }
    }
  }

  // denominator: reduce across the 16 lanes of each quad-row group
#pragma unroll
  for (int m = 1; m < 16; m <<= 1)
#pragma unroll
    for (int r = 0; r < 4; ++r)
      rden[r] += __shfl_xor(rden[r], m, 64);

  // write unnormalized fp32 partials + denominators
  float* const Op = sp ? Opart1 : Opart0;
  float* const dp = sp ? den1 : den0;
  const size_t ob = (size_t)(bn * 16 + it) * 64;
#pragma unroll
  for (int r = 0; r < 4; ++r) {
    const int il = wv * 16 + quad * 4 + r;
#pragma unroll
    for (int dt = 0; dt < 4; ++dt)
      Op[(ob + il) * 64 + dt * 16 + l15] = O[dt][r];
    if (l15 == 0) dp[ob + il] = rden[r];
  }
}

// ---------------------------------------------------------------------------
// combine j-split partials: AVb = bf16((O0+O1) / (d0+d1)). grid 1024.
// ---------------------------------------------------------------------------
__global__ __launch_bounds__(256) void attn_combine(
    const float* __restrict__ O0, const float* __restrict__ O1,
    const float* __restrict__ d0, const float* __restrict__ d1,
    unsigned short* __restrict__ AVb)
{
  const int blk = (int)blockIdx.x;           // bn*16 + it
  const int bn = blk >> 4, it = blk & 15;
  const int b = bn >> 4, n = bn & 15;
  const int tid = threadIdx.x;
  const int il = tid >> 2, ds = (tid & 3) * 16;
  const size_t base = ((size_t)blk * 64 + il) * 64 + ds;
  const float inv = 1.f / (d0[blk * 64 + il] + d1[blk * 64 + il]);
  short8 o0, o1;
#pragma unroll
  for (int g = 0; g < 2; ++g) {
    const float4 a = *(const float4*)(O0 + base + g * 8);
    const float4 bb = *(const float4*)(O1 + base + g * 8);
    const float4 a2 = *(const float4*)(O0 + base + g * 8 + 4);
    const float4 b2 = *(const float4*)(O1 + base + g * 8 + 4);
    short8& o = g ? o1 : o0;
    o[0] = (short)f2bf((a.x + bb.x) * inv);  o[1] = (short)f2bf((a.y + bb.y) * inv);
    o[2] = (short)f2bf((a.z + bb.z) * inv);  o[3] = (short)f2bf((a.w + bb.w) * inv);
    o[4] = (short)f2bf((a2.x + b2.x) * inv); o[5] = (short)f2bf((a2.y + b2.y) * inv);
    o[6] = (short)f2bf((a2.z + b2.z) * inv); o[7] = (short)f2bf((a2.w + b2.w) * inv);
  }
  unsigned short* op =
      AVb + ((size_t)(it * 64 + il) * BSZ + b) * DMODEL + n * DHEAD + ds;
  *(short8*)op = o0;
  *(short8*)(op + 8) = o1;
}

// ---------------------------------------------------------------------------
__global__ __launch_bounds__(256) void ln_kernel(
    float* __restrict__ X, const float* __restrict__ gw,
    const float* __restrict__ bw, unsigned short* __restrict__ bfo)
{
  const int row = blockIdx.x, tid = threadIdx.x;
  float* rp = X + (size_t)row * DMODEL;
  const float4 x = *(const float4*)(rp + tid * 4);
  float s = x.x + x.y + x.z + x.w;
  float q = x.x * x.x + x.y * x.y + x.z * x.z + x.w * x.w;
#pragma unroll
  for (int m = 1; m < 64; m <<= 1) {
    s += __shfl_xor(s, m, 64);
    q += __shfl_xor(q, m, 64);
  }
  __shared__ float ss[4], sq[4];
  if ((tid & 63) == 0) { ss[tid >> 6] = s; sq[tid >> 6] = q; }
  __syncthreads();
  s = ss[0] + ss[1] + ss[2] + ss[3];
  q = sq[0] + sq[1] + sq[2] + sq[3];
  const float mu = s * (1.f / DMODEL);
  const float var = q * (1.f / DMODEL) - mu * mu;
  const float rstd = rsqrtf(var + 1e-5f);
  const float4 g4 = *(const float4*)(gw + tid * 4);
  const float4 b4 = *(const float4*)(bw + tid * 4);
  float4 y;
  y.x = (x.x - mu) * rstd * g4.x + b4.x;
  y.y = (x.y - mu) * rstd * g4.y + b4.y;
  y.z = (x.z - mu) * rstd * g4.z + b4.z;
  y.w = (x.w - mu) * rstd * g4.w + b4.w;
  *(float4*)(rp + tid * 4) = y;
  if (bfo) {
    short4_t o;
    o[0] = (short)f2bf(y.x); o[1] = (short)f2bf(y.y);
    o[2] = (short)f2bf(y.z); o[3] = (short)f2bf(y.w);
    *(short4_t*)(bfo + (size_t)row * DMODEL + tid * 4) = o;
  }
}

// ---------------------------------------------------------------------------
extern "C" void kernel_launch(void* const* d_in, const int* in_sizes, int n_in,
                              void* d_out, int out_size, void* d_ws,
                              size_t ws_size, hipStream_t stream)
{
  const float* w       = (const float*)d_in[0];
  const float* r       = (const float*)d_in[1];
  const float* mems    = (const float*)d_in[2];
  const float* qkv_w   = (const float*)d_in[3];
  const float* r_net_w = (const float*)d_in[4];
  const float* o_w     = (const float*)d_in[5];
  const float* r_w_bias= (const float*)d_in[6];
  const float* r_r_bias= (const float*)d_in[7];
  const float* ln1_g   = (const float*)d_in[8];
  const float* ln1_b   = (const float*)d_in[9];
  const float* ff_w1   = (const float*)d_in[10];
  const float* ff_b1   = (const float*)d_in[11];
  const float* ff_w2   = (const float*)d_in[12];
  const float* ff_b2   = (const float*)d_in[13];
  const float* ln2_g   = (const float*)d_in[14];
  const float* ln2_b   = (const float*)d_in[15];
  float* out = (float*)d_out;

  // ---- workspace carve-up ----
  float* X1 = (float*)d_ws;                               // 4,194,304 f32
  unsigned short* Qh   = (unsigned short*)(X1 + 4194304); // 4,194,304 bf16
  unsigned short* Kh   = Qh + 4194304;                    // 8,388,608
  unsigned short* Vt   = Kh + 8388608;                    // 8,388,608
  unsigned short* Rk   = Vt + 8388608;                    // 2,097,152 (+8192 pad)
  unsigned short* Xcat = Rk + 2097152 + 8192;             // 8,388,608
  unsigned short* Wqkv = Xcat + 8388608;                  // 3,145,728
  unsigned short* Wr   = Wqkv + 3145728;                  // 1,048,576
  unsigned short* Wo   = Wr + 1048576;                    // 1,048,576
  unsigned short* W1   = Wo + 1048576;                    // 4,194,304
  unsigned short* W2   = W1 + 4194304;                    // 4,194,304
  float* den0 = (float*)(W2 + 4194304);                   // 65,536 f32
  float* den1 = den0 + 65536;                             // 65,536 f32
  unsigned short* AVb  = (unsigned short*)(den1 + 65536); // 4,194,304 bf16
  // aliases (disjoint lifetimes):
  unsigned short* Vh     = (unsigned short*)X1;  // qkv V (dead after transpose_v)
  unsigned short* Rb16   = AVb;                  // r bf16 (dead after rproj)
  float* Opart0          = (float*)X1;           // attn partial, split 0 (16MB)
  float* Opart1          = (float*)Xcat;         // attn partial, split 1 (16MB)
  unsigned short* X1b    = Qh;                   // ln1 bf16 (Qh dead after attn)
  unsigned short* H      = Kh;                   // ffn hidden (spans Kh+Vt)

  const dim3 blk(256);

  // prep: 2 launches
  cast_all<<<dim3(5120), blk, 0, stream>>>(mems, w, r, Xcat, Rb16);
  transpose_all<<<dim3(3328), blk, 0, stream>>>(
      qkv_w, r_net_w, o_w, ff_w1, ff_w2, Wqkv, Wr, Wo, W1, W2);

  // 1. QKV -> Qh/Kh bf16, Vh row-major; then V transpose
  mgemm<0, 128><<<dim3(24, 64), blk, 0, stream>>>(
      Xcat, Wqkv, nullptr, Qh, nullptr, nullptr, Kh, Vh, DMODEL, 3 * DMODEL);
  transpose_v<<<dim3(32, 64), blk, 0, stream>>>(Vh, Vt);
  // 2. R projection -> Rk bf16
  mgemm<1, 64><<<dim3(16, 16), blk, 0, stream>>>(
      Rb16, Wr, nullptr, Rk, nullptr, nullptr, nullptr, nullptr, DMODEL, DMODEL);
  // 3. MFMA flash attention (j-split) -> fp32 partials; combine -> AVb bf16
  attn_mfma<<<dim3(32, 64), blk, 0, stream>>>(
      Qh, Kh, Vt, Rk, r_w_bias, r_r_bias, Opart0, Opart1, den0, den1);
  attn_combine<<<dim3(1024), blk, 0, stream>>>(Opart0, Opart1, den0, den1, AVb);
  // 4. o-proj + residual -> X1 fp32; LN1 (+X1b bf16)
  mgemm<2, 64><<<dim3(16, 32), blk, 0, stream>>>(
      AVb, Wo, X1, nullptr, nullptr, w, nullptr, nullptr, DMODEL, DMODEL);
  ln_kernel<<<dim3(4096), blk, 0, stream>>>(X1, ln1_g, ln1_b, X1b);
  // 5. FFN up + relu -> H bf16
  mgemm<3, 128><<<dim3(32, 32), blk, 0, stream>>>(
      X1b, W1, nullptr, H, ff_b1, nullptr, nullptr, nullptr, DMODEL, DINNER);
  // 6. FFN down + bias + residual -> out fp32; LN2
  mgemm<4, 64><<<dim3(16, 32), blk, 0, stream>>>(
      H, W2, out, nullptr, ff_b2, X1, nullptr, nullptr, DINNER, DMODEL);
  ln_kernel<<<dim3(4096), blk, 0, stream>>>(out, ln2_g, ln2_b, nullptr);

  (void)in_sizes; (void)n_in; (void)out_size; (void)ws_size;
}